// Round 2
// baseline (938.468 us; speedup 1.0000x reference)
//
#include <hip/hip_runtime.h>

typedef __bf16 bf16;
typedef __bf16 bf16x8 __attribute__((ext_vector_type(8)));
typedef __bf16 bf16x4 __attribute__((ext_vector_type(4)));
typedef __bf16 bf16x2 __attribute__((ext_vector_type(2)));
typedef float f32x4 __attribute__((ext_vector_type(4)));

#define MFMA16(a, b, c) __builtin_amdgcn_mfma_f32_16x16x32_bf16((a), (b), (c), 0, 0, 0)

// ---------------------------------------------------------------------------
// fused weight fp32 -> bf16 conversion. dst regions are contiguous in ws, so
// dst index == 4*global chunk id. 147456 float4 chunks total = 576 blocks.
// ---------------------------------------------------------------------------
__global__ __launch_bounds__(256) void cvt_all(
    const float* __restrict__ s0, const float* __restrict__ s1, const float* __restrict__ s2,
    const float* __restrict__ s3, const float* __restrict__ s4, const float* __restrict__ s5,
    bf16* __restrict__ dst) {
    int g = blockIdx.x * 256 + threadIdx.x;
    const float* src;
    int local;
    if (g < 40960)       { src = s0; local = g; }
    else if (g < 49152)  { src = s1; local = g - 40960; }
    else if (g < 86016)  { src = s2; local = g - 49152; }
    else if (g < 98304)  { src = s3; local = g - 86016; }
    else if (g < 122880) { src = s4; local = g - 98304; }
    else                 { src = s5; local = g - 122880; }
    float4 v = *(const float4*)(src + (long)local * 4);
    bf16x4 o = {(bf16)v.x, (bf16)v.y, (bf16)v.z, (bf16)v.w};
    *(bf16x4*)(dst + (long)g * 4) = o;
}

// ---------------------------------------------------------------------------
// helpers
// ---------------------------------------------------------------------------
__device__ __forceinline__ float allsum64(float v) {
#pragma unroll
    for (int m = 1; m < 64; m <<= 1) v += __shfl_xor(v, m, 64);
    return v;
}

// LayerNorm of one 128-elem bf16 row in LDS; one wave per row
__device__ __forceinline__ void ln_bf16_row(bf16* row, const float* g, const float* b,
                                            const float* add, int lane) {
    float v0 = (float)row[lane], v1 = (float)row[lane + 64];
    float mu = allsum64(v0 + v1) * (1.0f / 128.0f);
    float c0 = v0 - mu, c1 = v1 - mu;
    float var = allsum64(c0 * c0 + c1 * c1) * (1.0f / 128.0f);
    float rs = rsqrtf(var + 1e-5f);
    float o0 = c0 * rs * g[lane] + b[lane];
    float o1 = c1 * rs * g[lane + 64] + b[lane + 64];
    if (add) { o0 += add[lane]; o1 += add[lane + 64]; }
    row[lane] = (bf16)o0;
    row[lane + 64] = (bf16)o1;
}

__device__ __forceinline__ void ln_f32_row(float* row, const float* g, const float* b, int lane) {
    float v0 = row[lane], v1 = row[lane + 64];
    float mu = allsum64(v0 + v1) * (1.0f / 128.0f);
    float c0 = v0 - mu, c1 = v1 - mu;
    float var = allsum64(c0 * c0 + c1 * c1) * (1.0f / 128.0f);
    float rs = rsqrtf(var + 1e-5f);
    row[lane] = c0 * rs * g[lane] + b[lane];
    row[lane + 64] = c1 * rs * g[lane + 64] + b[lane + 64];
}

// register prefetch of 32 rows x 128 k of fp32 global x (4 float4 per thread)
__device__ __forceinline__ void xload(const float* __restrict__ src, long sstride, long kofs,
                                      long rowbase, int t, float4 (&xv)[4]) {
    const int f4 = (t & 31) * 4;
    const int r0 = t >> 5;
#pragma unroll
    for (int i = 0; i < 4; ++i)
        xv[i] = *(const float4*)(src + (rowbase + r0 + i * 8) * sstride + kofs + f4);
}

// convert + store prefetched regs into bf16 LDS [32][136]
__device__ __forceinline__ void xstore(bf16* __restrict__ dst, int t, const float4 (&xv)[4]) {
    const int f4 = (t & 31) * 4;
    const int r0 = t >> 5;
#pragma unroll
    for (int i = 0; i < 4; ++i) {
        bf16x4 o = {(bf16)xv[i].x, (bf16)xv[i].y, (bf16)xv[i].z, (bf16)xv[i].w};
        *(bf16x4*)(dst + (r0 + i * 8) * 136 + f4) = o;
    }
}

// 32(M) x 128(N) x 128(K) MFMA tile: wave wid owns cols [wid*32, wid*32+32)
// A from LDS; B fragments loaded DIRECTLY from global (L2-resident weights,
// layout [out_col][k] with row stride wstride).
__device__ __forceinline__ void gemm_k128_gw(const bf16* __restrict__ A, int astride,
                                             const bf16* __restrict__ W, int wstride,
                                             int lane, int wid, f32x4 acc[2][2]) {
    const int m = lane & 15;
    const int kq = (lane >> 4) * 8;
    const bf16* a0p = A + m * astride + kq;
    const bf16* a1p = a0p + 16 * astride;
    const bf16* b0p = W + (long)(wid * 32 + m) * wstride + kq;
    const bf16* b1p = b0p + 16 * wstride;
#pragma unroll
    for (int kc = 0; kc < 4; ++kc) {
        int k = kc * 32;
        bf16x8 a0 = *(const bf16x8*)(a0p + k);
        bf16x8 a1 = *(const bf16x8*)(a1p + k);
        bf16x8 b0 = *(const bf16x8*)(b0p + k);
        bf16x8 b1 = *(const bf16x8*)(b1p + k);
        acc[0][0] = MFMA16(a0, b0, acc[0][0]);
        acc[0][1] = MFMA16(a0, b1, acc[0][1]);
        acc[1][0] = MFMA16(a1, b0, acc[1][0]);
        acc[1][1] = MFMA16(a1, b1, acc[1][1]);
    }
}

template <typename F>
__device__ __forceinline__ void foreach_acc(const f32x4 (&acc)[2][2], int lane, int wid, F&& f) {
    const int rlo = (lane >> 4) * 4;
    const int cl = lane & 15;
#pragma unroll
    for (int mt = 0; mt < 2; ++mt)
#pragma unroll
        for (int nt = 0; nt < 2; ++nt)
#pragma unroll
            for (int j = 0; j < 4; ++j)
                f(mt * 16 + rlo + j, wid * 32 + nt * 16 + cl, acc[mt][nt][j]);
}

__device__ __forceinline__ void zacc(f32x4 (&a)[2][2]) {
    const f32x4 z = {0.f, 0.f, 0.f, 0.f};
    a[0][0] = z; a[0][1] = z; a[1][0] = z; a[1][1] = z;
}

// add per-col bias to acc: cols wid*32+cl (nt=0) and +16 (nt=1)
__device__ __forceinline__ void add_bias(f32x4 (&a)[2][2], const float* __restrict__ b,
                                         int lane, int wid) {
    float b0 = b[wid * 32 + (lane & 15)];
    float b1 = b[wid * 32 + (lane & 15) + 16];
#pragma unroll
    for (int mt = 0; mt < 2; ++mt)
#pragma unroll
        for (int j = 0; j < 4; ++j) { a[mt][0][j] += b0; a[mt][1][j] += b1; }
}

// ---------------------------------------------------------------------------
// ONE fused kernel per 32-row tile: proj -> attn -> ffn -> gate.
// P, X1, X2 never touch HBM. Weights direct-from-L2 (no staging barriers).
// LDS: sP 26112 + sX1 26112 + sA 8704 + sH 16896 = 77824 B -> 2 WG/CU.
// Layout: stream n of a 3x128 row lives at [row*408 + n*136 .. +128).
// ---------------------------------------------------------------------------
__global__ __launch_bounds__(256, 2) void fused_kernel(
    const float* __restrict__ xs, const float* __restrict__ xg, const float* __restrict__ xf,
    const bf16* __restrict__ wsp, const bf16* __restrict__ wgf,
    const float* __restrict__ projb, const float* __restrict__ pg_, const float* __restrict__ pb_,
    const float* __restrict__ memb,
    const bf16* __restrict__ wqkv, const bf16* __restrict__ wout,
    const float* __restrict__ inb, const float* __restrict__ outb,
    const float* __restrict__ ag_, const float* __restrict__ ab_,
    const bf16* __restrict__ w1, const bf16* __restrict__ w2,
    const float* __restrict__ fb1, const float* __restrict__ fb2,
    const float* __restrict__ fg_, const float* __restrict__ fbb_,
    const float* __restrict__ gw, const float* __restrict__ gb,
    float* __restrict__ out) {
    const int t = threadIdx.x, lane = t & 63, wid = t >> 6;
    const long rowbase = (long)blockIdx.x * 32;
    __shared__ __align__(16) bf16 sP[32 * 408];    // P; later X2
    __shared__ __align__(16) bf16 sX1[32 * 408];   // x1, all 3 streams
    __shared__ __align__(16) bf16 sA[32 * 136];    // x-staging / attn O
    __shared__ __align__(16) bf16 sH[32 * 264];    // ffn hidden; f32 LN alias
    float* sHf = (float*)sH;                       // [32][132]

    // ================= phase 1: projections -> sP =================
    {
        f32x4 acc[2][2];
        zacc(acc);
        float4 xv[4];
        xload(xs, 1280, 0, rowbase, t, xv);
        for (int sc = 0; sc < 10; ++sc) {
            __syncthreads();                 // prior gemm done reading sA
            xstore(sA, t, xv);
            __syncthreads();
            if (sc < 9) xload(xs, 1280, (sc + 1) * 128, rowbase, t, xv);
            else        xload(xg, 128, 0, rowbase, t, xv);
            gemm_k128_gw(sA, 136, wsp + sc * 128, 1280, lane, wid, acc);
        }
        foreach_acc(acc, lane, wid, [&](int row, int col, float v) {
            sP[row * 408 + col] = (bf16)(v + projb[col]);
        });
        for (int g2 = 0; g2 < 2; ++g2) {
            __syncthreads();
            xstore(sA, t, xv);
            __syncthreads();
            if (g2 == 0) xload(xf, 128, 0, rowbase, t, xv);
            zacc(acc);
            gemm_k128_gw(sA, 136, wgf + g2 * 16384, 128, lane, wid, acc);
            foreach_acc(acc, lane, wid, [&](int row, int col, float v) {
                sP[row * 408 + (1 + g2) * 136 + col] = (bf16)(v + projb[(1 + g2) * 128 + col]);
            });
        }
        __syncthreads();
        for (int p = wid; p < 96; p += 4) {
            int r = p & 31, n = p >> 5;
            ln_bf16_row(sP + r * 408 + n * 136, pg_ + n * 128, pb_ + n * 128, memb + n * 128, lane);
        }
        __syncthreads();
    }

    // ================= phase 2: attention -> sX1 =================
    for (int n = 0; n < 3; ++n) {
        const int m0 = (n == 0) ? 1 : 0;
        const int m1 = (n == 2) ? 1 : 2;
        const bf16* Wn = wqkv + (long)n * 384 * 128;

        f32x4 aq[2][2], ak0[2][2], ak1[2][2];
        zacc(aq);
        gemm_k128_gw(sP + n * 136, 408, Wn, 128, lane, wid, aq);
        add_bias(aq, inb + n * 384, lane, wid);
        zacc(ak0); zacc(ak1);
        gemm_k128_gw(sP + m0 * 136, 408, Wn + 16384, 128, lane, wid, ak0);
        gemm_k128_gw(sP + m1 * 136, 408, Wn + 16384, 128, lane, wid, ak1);
        add_bias(ak0, inb + n * 384 + 128, lane, wid);
        add_bias(ak1, inb + n * 384 + 128, lane, wid);

        // scores + softmax: head = wid; reduce over 16 lanes of the quad
        float a0_[2][4], a1_[2][4];
        const float scl = 0.17677669529663687f;  // 1/sqrt(32)
#pragma unroll
        for (int mt = 0; mt < 2; ++mt)
#pragma unroll
            for (int j = 0; j < 4; ++j) {
                float d0 = aq[mt][0][j] * ak0[mt][0][j] + aq[mt][1][j] * ak0[mt][1][j];
                float d1 = aq[mt][0][j] * ak1[mt][0][j] + aq[mt][1][j] * ak1[mt][1][j];
#pragma unroll
                for (int m = 1; m < 16; m <<= 1) {
                    d0 += __shfl_xor(d0, m, 64);
                    d1 += __shfl_xor(d1, m, 64);
                }
                d0 *= scl; d1 *= scl;
                float mx = fmaxf(d0, d1);
                float e0 = expf(d0 - mx), e1 = expf(d1 - mx);
                float inv = 1.f / (e0 + e1);
                a0_[mt][j] = e0 * inv;
                a1_[mt][j] = e1 * inv;
            }

        f32x4 av0[2][2], av1[2][2];
        zacc(av0); zacc(av1);
        gemm_k128_gw(sP + m0 * 136, 408, Wn + 32768, 128, lane, wid, av0);
        gemm_k128_gw(sP + m1 * 136, 408, Wn + 32768, 128, lane, wid, av1);
        add_bias(av0, inb + n * 384 + 256, lane, wid);
        add_bias(av1, inb + n * 384 + 256, lane, wid);

        __syncthreads();   // previous n fully done reading sA
        {
            const int rlo = (lane >> 4) * 4, cl = lane & 15;
#pragma unroll
            for (int mt = 0; mt < 2; ++mt)
#pragma unroll
                for (int nt = 0; nt < 2; ++nt)
#pragma unroll
                    for (int j = 0; j < 4; ++j) {
                        float o = a0_[mt][j] * av0[mt][nt][j] + a1_[mt][j] * av1[mt][nt][j];
                        sA[(mt * 16 + rlo + j) * 136 + wid * 32 + nt * 16 + cl] = (bf16)o;
                    }
        }
        __syncthreads();
        f32x4 acc[2][2];
        zacc(acc);
        gemm_k128_gw(sA, 136, wout + (long)n * 16384, 128, lane, wid, acc);
        foreach_acc(acc, lane, wid, [&](int row, int col, float v) {
            float val = v + outb[n * 128 + col] + (float)sP[row * 408 + n * 136 + col];
            sX1[row * 408 + n * 136 + col] = (bf16)val;
        });
    }
    __syncthreads();
    for (int p = wid; p < 96; p += 4) {
        int r = p & 31, n = p >> 5;
        ln_bf16_row(sX1 + r * 408 + n * 136, ag_ + n * 128, ab_ + n * 128, nullptr, lane);
    }

    // ================= phase 3: FFN -> x2 into sP =================
    for (int n = 0; n < 3; ++n) {
        __syncthreads();   // n=0: LN(sX1) done; n>0: prior sHf reads + sP cvt done
        f32x4 fa[2][2];
#pragma unroll
        for (int half = 0; half < 2; ++half) {
            zacc(fa);
            gemm_k128_gw(sX1 + n * 136, 408, w1 + (long)(n * 256 + half * 128) * 128, 128,
                         lane, wid, fa);
            foreach_acc(fa, lane, wid, [&](int row, int col, float v) {
                float x = v + fb1[n * 256 + half * 128 + col];
                float ge = 0.5f * x * (1.0f + erff(x * 0.70710678118654752f));
                sH[row * 264 + half * 128 + col] = (bf16)ge;
            });
        }
        __syncthreads();   // sH complete
        zacc(fa);
        gemm_k128_gw(sH, 264, w2 + (long)n * 32768, 256, lane, wid, fa);
        gemm_k128_gw(sH + 128, 264, w2 + (long)n * 32768 + 128, 256, lane, wid, fa);
        __syncthreads();   // all sH reads done before f32 alias writes
        foreach_acc(fa, lane, wid, [&](int row, int col, float v) {
            sHf[row * 132 + col] = v + fb2[n * 128 + col] + (float)sX1[row * 408 + n * 136 + col];
        });
        __syncthreads();
        for (int p = wid; p < 32; p += 4)
            ln_f32_row(sHf + p * 132, fg_ + n * 128, fbb_ + n * 128, lane);
        __syncthreads();
        // f32 -> bf16 into sP (x2 buffer)
#pragma unroll
        for (int i = 0; i < 8; ++i) {
            int lin = t + i * 256;           // 0..2047 pairs
            int r = lin >> 6, c2 = (lin & 63) * 2;
            bf16x2 o = {(bf16)sHf[r * 132 + c2], (bf16)sHf[r * 132 + c2 + 1]};
            *(bf16x2*)(sP + r * 408 + n * 136 + c2) = o;
        }
    }
    __syncthreads();

    // ================= phase 4: gates + fused output =================
    float p0[6], p1[6], p2[6];
    const int e = lane * 6;
#pragma unroll
    for (int i = 0; i < 6; ++i) {
        p0[i] = gw[e + i];
        p1[i] = gw[384 + e + i];
        p2[i] = gw[768 + e + i];
    }
    for (int r = wid; r < 32; r += 4) {
        const bf16* xr = sP + r * 408;
        float l0 = 0.f, l1 = 0.f, l2 = 0.f;
#pragma unroll
        for (int i = 0; i < 6; ++i) {
            int f = e + i;
            float x = (float)xr[(f >> 7) * 136 + (f & 127)];
            l0 += x * p0[i]; l1 += x * p1[i]; l2 += x * p2[i];
        }
        l0 = allsum64(l0) + gb[0];
        l1 = allsum64(l1) + gb[1];
        l2 = allsum64(l2) + gb[2];
        float mx = fmaxf(l0, fmaxf(l1, l2));
        float e0 = expf(l0 - mx), e1 = expf(l1 - mx), e2 = expf(l2 - mx);
        float inv = 1.f / (e0 + e1 + e2);
        float g0 = e0 * inv, g1 = e1 * inv, g2 = e2 * inv;
        float o0 = g0 * (float)xr[lane] + g1 * (float)xr[136 + lane] + g2 * (float)xr[272 + lane];
        float o1 = g0 * (float)xr[64 + lane] + g1 * (float)xr[200 + lane] +
                   g2 * (float)xr[336 + lane];
        out[(rowbase + r) * 128 + lane] = o0;
        out[(rowbase + r) * 128 + 64 + lane] = o1;
    }
}

// ---------------------------------------------------------------------------
extern "C" void kernel_launch(void* const* d_in, const int* in_sizes, int n_in,
                              void* d_out, int out_size, void* d_ws, size_t ws_size,
                              hipStream_t stream) {
    const float* xs = (const float*)d_in[0];
    const float* xg = (const float*)d_in[1];
    const float* xf = (const float*)d_in[2];
    const float* w_sp = (const float*)d_in[3];
    const float* w_gf = (const float*)d_in[4];
    const float* proj_b = (const float*)d_in[5];
    const float* proj_g = (const float*)d_in[6];
    const float* proj_bb = (const float*)d_in[7];
    const float* mod_emb = (const float*)d_in[8];
    const float* in_w = (const float*)d_in[9];
    const float* in_b = (const float*)d_in[10];
    const float* out_w = (const float*)d_in[11];
    const float* out_b = (const float*)d_in[12];
    const float* attn_g = (const float*)d_in[13];
    const float* attn_b = (const float*)d_in[14];
    const float* ffn_w1 = (const float*)d_in[15];
    const float* ffn_b1 = (const float*)d_in[16];
    const float* ffn_w2 = (const float*)d_in[17];
    const float* ffn_b2 = (const float*)d_in[18];
    const float* ffn_g = (const float*)d_in[19];
    const float* ffn_bb = (const float*)d_in[20];
    const float* gate_w = (const float*)d_in[21];
    const float* gate_b = (const float*)d_in[22];

    const int B = in_sizes[1] / 128;  // 65536

    bf16* wb = (bf16*)d_ws;
    bf16* wsp = wb;                    // 163840 elems
    bf16* wgf = wb + 163840;           // 32768
    bf16* wqkv = wb + 196608;          // 147456
    bf16* wout = wb + 344064;          // 49152
    bf16* w1 = wb + 393216;            // 98304
    bf16* w2 = wb + 491520;            // 98304

    cvt_all<<<576, 256, 0, stream>>>(w_sp, w_gf, in_w, out_w, ffn_w1, ffn_w2, wb);
    fused_kernel<<<B / 32, 256, 0, stream>>>(
        xs, xg, xf, wsp, wgf, proj_b, proj_g, proj_bb, mod_emb,
        wqkv, wout, in_b, out_b, attn_g, attn_b,
        ffn_w1 ? w1 : w1, w2, ffn_b1, ffn_b2, ffn_g, ffn_bb,
        gate_w, gate_b, (float*)d_out);
}

// Round 3
// 829.744 us; speedup vs baseline: 1.1310x; 1.1310x over previous
//
#include <hip/hip_runtime.h>

typedef __bf16 bf16;
typedef __bf16 bf16x8 __attribute__((ext_vector_type(8)));
typedef __bf16 bf16x4 __attribute__((ext_vector_type(4)));
typedef __bf16 bf16x2 __attribute__((ext_vector_type(2)));
typedef float f32x4 __attribute__((ext_vector_type(4)));

#define MFMA16(a, b, c) __builtin_amdgcn_mfma_f32_16x16x32_bf16((a), (b), (c), 0, 0, 0)

// ---------------------------------------------------------------------------
// fused weight fp32 -> bf16 conversion. 147456 float4 chunks = 576 blocks.
// ---------------------------------------------------------------------------
__global__ __launch_bounds__(256) void cvt_all(
    const float* __restrict__ s0, const float* __restrict__ s1, const float* __restrict__ s2,
    const float* __restrict__ s3, const float* __restrict__ s4, const float* __restrict__ s5,
    bf16* __restrict__ dst) {
    int g = blockIdx.x * 256 + threadIdx.x;
    const float* src;
    int local;
    if (g < 40960)       { src = s0; local = g; }
    else if (g < 49152)  { src = s1; local = g - 40960; }
    else if (g < 86016)  { src = s2; local = g - 49152; }
    else if (g < 98304)  { src = s3; local = g - 86016; }
    else if (g < 122880) { src = s4; local = g - 98304; }
    else                 { src = s5; local = g - 122880; }
    float4 v = *(const float4*)(src + (long)local * 4);
    bf16x4 o = {(bf16)v.x, (bf16)v.y, (bf16)v.z, (bf16)v.w};
    *(bf16x4*)(dst + (long)g * 4) = o;
}

// ---------------------------------------------------------------------------
// helpers
// ---------------------------------------------------------------------------
__device__ __forceinline__ float allsum64(float v) {
#pragma unroll
    for (int m = 1; m < 64; m <<= 1) v += __shfl_xor(v, m, 64);
    return v;
}

// 16-lane-group LayerNorm: each 16-lane group normalizes one 128-elem bf16 row
// (8 elems/lane). 4 rows per wave in parallel; 4-step reduce.
__device__ __forceinline__ void ln16_bf16(bf16* row, const float* g, const float* b,
                                          const float* add, int l16) {
    bf16x8 v = *(const bf16x8*)(row + l16 * 8);
    float f[8];
#pragma unroll
    for (int i = 0; i < 8; ++i) f[i] = (float)v[i];
    float s = 0.f;
#pragma unroll
    for (int i = 0; i < 8; ++i) s += f[i];
#pragma unroll
    for (int m = 1; m < 16; m <<= 1) s += __shfl_xor(s, m, 64);
    float mu = s * (1.0f / 128.0f);
    float q = 0.f;
#pragma unroll
    for (int i = 0; i < 8; ++i) { f[i] -= mu; q += f[i] * f[i]; }
#pragma unroll
    for (int m = 1; m < 16; m <<= 1) q += __shfl_xor(q, m, 64);
    float rs = rsqrtf(q * (1.0f / 128.0f) + 1e-5f);
    float4 g0 = *(const float4*)(g + l16 * 8), g1 = *(const float4*)(g + l16 * 8 + 4);
    float4 b0 = *(const float4*)(b + l16 * 8), b1 = *(const float4*)(b + l16 * 8 + 4);
    float o[8];
    o[0] = f[0] * rs * g0.x + b0.x; o[1] = f[1] * rs * g0.y + b0.y;
    o[2] = f[2] * rs * g0.z + b0.z; o[3] = f[3] * rs * g0.w + b0.w;
    o[4] = f[4] * rs * g1.x + b1.x; o[5] = f[5] * rs * g1.y + b1.y;
    o[6] = f[6] * rs * g1.z + b1.z; o[7] = f[7] * rs * g1.w + b1.w;
    if (add) {
        float4 a0 = *(const float4*)(add + l16 * 8), a1 = *(const float4*)(add + l16 * 8 + 4);
        o[0] += a0.x; o[1] += a0.y; o[2] += a0.z; o[3] += a0.w;
        o[4] += a1.x; o[5] += a1.y; o[6] += a1.z; o[7] += a1.w;
    }
    bf16x8 w;
#pragma unroll
    for (int i = 0; i < 8; ++i) w[i] = (bf16)o[i];
    *(bf16x8*)(row + l16 * 8) = w;
}

__device__ __forceinline__ void ln16_f32(float* row, const float* g, const float* b, int l16) {
    float4 u0 = *(const float4*)(row + l16 * 8), u1 = *(const float4*)(row + l16 * 8 + 4);
    float f[8] = {u0.x, u0.y, u0.z, u0.w, u1.x, u1.y, u1.z, u1.w};
    float s = 0.f;
#pragma unroll
    for (int i = 0; i < 8; ++i) s += f[i];
#pragma unroll
    for (int m = 1; m < 16; m <<= 1) s += __shfl_xor(s, m, 64);
    float mu = s * (1.0f / 128.0f);
    float q = 0.f;
#pragma unroll
    for (int i = 0; i < 8; ++i) { f[i] -= mu; q += f[i] * f[i]; }
#pragma unroll
    for (int m = 1; m < 16; m <<= 1) q += __shfl_xor(q, m, 64);
    float rs = rsqrtf(q * (1.0f / 128.0f) + 1e-5f);
    float4 g0 = *(const float4*)(g + l16 * 8), g1 = *(const float4*)(g + l16 * 8 + 4);
    float4 b0 = *(const float4*)(b + l16 * 8), b1 = *(const float4*)(b + l16 * 8 + 4);
    float4 r0, r1;
    r0.x = f[0] * rs * g0.x + b0.x; r0.y = f[1] * rs * g0.y + b0.y;
    r0.z = f[2] * rs * g0.z + b0.z; r0.w = f[3] * rs * g0.w + b0.w;
    r1.x = f[4] * rs * g1.x + b1.x; r1.y = f[5] * rs * g1.y + b1.y;
    r1.z = f[6] * rs * g1.z + b1.z; r1.w = f[7] * rs * g1.w + b1.w;
    *(float4*)(row + l16 * 8) = r0;
    *(float4*)(row + l16 * 8 + 4) = r1;
}

// register prefetch of 32 rows x 128 k of fp32 global x (4 float4 per thread)
__device__ __forceinline__ void xload(const float* __restrict__ src, long sstride, long kofs,
                                      long rowbase, int t, float4 (&xv)[4]) {
    const int f4 = (t & 31) * 4;
    const int r0 = t >> 5;
#pragma unroll
    for (int i = 0; i < 4; ++i)
        xv[i] = *(const float4*)(src + (rowbase + r0 + i * 8) * sstride + kofs + f4);
}

// convert + store prefetched regs into bf16 LDS [32][136]
__device__ __forceinline__ void xstore(bf16* __restrict__ dst, int t, const float4 (&xv)[4]) {
    const int f4 = (t & 31) * 4;
    const int r0 = t >> 5;
#pragma unroll
    for (int i = 0; i < 4; ++i) {
        bf16x4 o = {(bf16)xv[i].x, (bf16)xv[i].y, (bf16)xv[i].z, (bf16)xv[i].w};
        *(bf16x4*)(dst + (r0 + i * 8) * 136 + f4) = o;
    }
}

// 32(M) x 128(N) x 128(K) MFMA tile: wave wid owns cols [wid*32, wid*32+32)
// A from LDS; B fragments loaded DIRECTLY from global (L2-resident weights).
__device__ __forceinline__ void gemm_k128_gw(const bf16* __restrict__ A, int astride,
                                             const bf16* __restrict__ W, int wstride,
                                             int lane, int wid, f32x4 acc[2][2]) {
    const int m = lane & 15;
    const int kq = (lane >> 4) * 8;
    const bf16* a0p = A + m * astride + kq;
    const bf16* a1p = a0p + 16 * astride;
    const bf16* b0p = W + (long)(wid * 32 + m) * wstride + kq;
    const bf16* b1p = b0p + 16 * wstride;
#pragma unroll
    for (int kc = 0; kc < 4; ++kc) {
        int k = kc * 32;
        bf16x8 a0 = *(const bf16x8*)(a0p + k);
        bf16x8 a1 = *(const bf16x8*)(a1p + k);
        bf16x8 b0 = *(const bf16x8*)(b0p + k);
        bf16x8 b1 = *(const bf16x8*)(b1p + k);
        acc[0][0] = MFMA16(a0, b0, acc[0][0]);
        acc[0][1] = MFMA16(a0, b1, acc[0][1]);
        acc[1][0] = MFMA16(a1, b0, acc[1][0]);
        acc[1][1] = MFMA16(a1, b1, acc[1][1]);
    }
}

template <typename F>
__device__ __forceinline__ void foreach_acc(const f32x4 (&acc)[2][2], int lane, int wid, F&& f) {
    const int rlo = (lane >> 4) * 4;
    const int cl = lane & 15;
#pragma unroll
    for (int mt = 0; mt < 2; ++mt)
#pragma unroll
        for (int nt = 0; nt < 2; ++nt)
#pragma unroll
            for (int j = 0; j < 4; ++j)
                f(mt * 16 + rlo + j, wid * 32 + nt * 16 + cl, acc[mt][nt][j]);
}

__device__ __forceinline__ void zacc(f32x4 (&a)[2][2]) {
    const f32x4 z = {0.f, 0.f, 0.f, 0.f};
    a[0][0] = z; a[0][1] = z; a[1][0] = z; a[1][1] = z;
}

__device__ __forceinline__ void add_bias(f32x4 (&a)[2][2], const float* __restrict__ b,
                                         int lane, int wid) {
    float b0 = b[wid * 32 + (lane & 15)];
    float b1 = b[wid * 32 + (lane & 15) + 16];
#pragma unroll
    for (int mt = 0; mt < 2; ++mt)
#pragma unroll
        for (int j = 0; j < 4; ++j) { a[mt][0][j] += b0; a[mt][1][j] += b1; }
}

// ---------------------------------------------------------------------------
// ONE fused kernel per 32-row tile: proj -> attn -> ffn -> gate.
// LDS: sP 26112 + sS 17408 = 43520 B -> 3 WG/CU.
// sP holds P -> x1 -> x2 in slots [row*408 + n*136].
// sS is double-buffered scratch: x-stage halves (ph1), attn-O halves (ph2),
// ffn hidden [32][264] / f32 LN buffer [32][132] (ph3).
// x1 lives in 24 VGPRs (bf16 pairs) during attention.
// ---------------------------------------------------------------------------
__global__ __launch_bounds__(256, 3) void fused_kernel(
    const float* __restrict__ xs, const float* __restrict__ xg, const float* __restrict__ xf,
    const bf16* __restrict__ wsp, const bf16* __restrict__ wgf,
    const float* __restrict__ projb, const float* __restrict__ pg_, const float* __restrict__ pb_,
    const float* __restrict__ memb,
    const bf16* __restrict__ wqkv, const bf16* __restrict__ wout,
    const float* __restrict__ inb, const float* __restrict__ outb,
    const float* __restrict__ ag_, const float* __restrict__ ab_,
    const bf16* __restrict__ w1, const bf16* __restrict__ w2,
    const float* __restrict__ fb1, const float* __restrict__ fb2,
    const float* __restrict__ fg_, const float* __restrict__ fbb_,
    const float* __restrict__ gw, const float* __restrict__ gb,
    float* __restrict__ out) {
    const int t = threadIdx.x, lane = t & 63, wid = t >> 6;
    const long rowbase = (long)blockIdx.x * 32;
    __shared__ __align__(16) bf16 sP[32 * 408];
    __shared__ __align__(16) bf16 sS[2 * 32 * 136];
    bf16* sH = sS;                 // [32][264] ffn hidden
    float* sHf = (float*)sS;       // [32][132] f32 LN buffer

    // ================= phase 1: projections -> sP =================
    {
        f32x4 acc[2][2];
        zacc(acc);
        float4 xv[4];
        xload(xs, 1280, 0, rowbase, t, xv);          // x_0
        xstore(sS, t, xv);                           // buf0
        xload(xs, 1280, 128, rowbase, t, xv);        // x_1
        __syncthreads();
        for (int sc = 0; sc < 12; ++sc) {
            const int cur = sc & 1;
            if (sc < 11) {
                xstore(sS + (cur ^ 1) * 4352, t, xv);            // x_{sc+1}
                if (sc <= 7)      xload(xs, 1280, (sc + 2) * 128, rowbase, t, xv);
                else if (sc == 8) xload(xg, 128, 0, rowbase, t, xv);
                else if (sc == 9) xload(xf, 128, 0, rowbase, t, xv);
            }
            const bf16* W = (sc < 10) ? (wsp + sc * 128) : (wgf + (long)(sc - 10) * 16384);
            const int ws_ = (sc < 10) ? 1280 : 128;
            gemm_k128_gw(sS + cur * 4352, 136, W, ws_, lane, wid, acc);
            if (sc >= 9) {
                const int sl = sc - 9;
                foreach_acc(acc, lane, wid, [&](int row, int col, float v) {
                    sP[row * 408 + sl * 136 + col] = (bf16)(v + projb[sl * 128 + col]);
                });
                zacc(acc);
            }
            __syncthreads();
        }
        // LN(P) + mod_emb: 96 rows, 16 rows per pass (4 waves x 4 groups)
#pragma unroll
        for (int it = 0; it < 6; ++it) {
            int p = it * 16 + wid * 4 + (lane >> 4);
            int r = p & 31, nn = p >> 5;
            ln16_bf16(sP + r * 408 + nn * 136, pg_ + nn * 128, pb_ + nn * 128,
                      memb + nn * 128, lane & 15);
        }
        __syncthreads();
    }

    // ================= phase 2: attention; x1 -> regs =================
    bf16x2 x1r[3][8];
    {
        const int rlo = (lane >> 4) * 4, cl = lane & 15;
#pragma unroll
        for (int n = 0; n < 3; ++n) {
            const int m0 = (n == 0) ? 1 : 0;
            const int m1 = (n == 2) ? 1 : 2;
            const bf16* Wn = wqkv + (long)n * 384 * 128;

            f32x4 aq[2][2], ak0[2][2], ak1[2][2];
            zacc(aq);
            gemm_k128_gw(sP + n * 136, 408, Wn, 128, lane, wid, aq);
            add_bias(aq, inb + n * 384, lane, wid);
            zacc(ak0); zacc(ak1);
            gemm_k128_gw(sP + m0 * 136, 408, Wn + 16384, 128, lane, wid, ak0);
            gemm_k128_gw(sP + m1 * 136, 408, Wn + 16384, 128, lane, wid, ak1);
            add_bias(ak0, inb + n * 384 + 128, lane, wid);
            add_bias(ak1, inb + n * 384 + 128, lane, wid);

            float a0_[2][4], a1_[2][4];
            const float scl = 0.17677669529663687f;  // 1/sqrt(32)
#pragma unroll
            for (int mt = 0; mt < 2; ++mt)
#pragma unroll
                for (int j = 0; j < 4; ++j) {
                    float d0 = aq[mt][0][j] * ak0[mt][0][j] + aq[mt][1][j] * ak0[mt][1][j];
                    float d1 = aq[mt][0][j] * ak1[mt][0][j] + aq[mt][1][j] * ak1[mt][1][j];
#pragma unroll
                    for (int m = 1; m < 16; m <<= 1) {
                        d0 += __shfl_xor(d0, m, 64);
                        d1 += __shfl_xor(d1, m, 64);
                    }
                    d0 *= scl; d1 *= scl;
                    float mx = fmaxf(d0, d1);
                    float e0 = expf(d0 - mx), e1 = expf(d1 - mx);
                    float inv = 1.f / (e0 + e1);
                    a0_[mt][j] = e0 * inv;
                    a1_[mt][j] = e1 * inv;
                }

            f32x4 av0[2][2], av1[2][2];
            zacc(av0); zacc(av1);
            gemm_k128_gw(sP + m0 * 136, 408, Wn + 32768, 128, lane, wid, av0);
            gemm_k128_gw(sP + m1 * 136, 408, Wn + 32768, 128, lane, wid, av1);
            add_bias(av0, inb + n * 384 + 256, lane, wid);
            add_bias(av1, inb + n * 384 + 256, lane, wid);

            // O into scratch half (alternating) — no pre-barrier needed:
            // last reads of this half are >=2 barriers back.
            bf16* sO = sS + (n & 1) * 4352;
#pragma unroll
            for (int mt = 0; mt < 2; ++mt)
#pragma unroll
                for (int nt = 0; nt < 2; ++nt)
#pragma unroll
                    for (int j = 0; j < 4; ++j) {
                        float o = a0_[mt][j] * av0[mt][nt][j] + a1_[mt][j] * av1[mt][nt][j];
                        sO[(mt * 16 + rlo + j) * 136 + wid * 32 + nt * 16 + cl] = (bf16)o;
                    }
            __syncthreads();
            f32x4 acc[2][2];
            zacc(acc);
            gemm_k128_gw(sO, 136, wout + (long)n * 16384, 128, lane, wid, acc);
            // x1 = o + outb + P (residual) -> registers as bf16 pairs
#pragma unroll
            for (int mt = 0; mt < 2; ++mt)
#pragma unroll
                for (int nt = 0; nt < 2; ++nt)
#pragma unroll
                    for (int j = 0; j < 4; ++j) {
                        int row = mt * 16 + rlo + j, col = wid * 32 + nt * 16 + cl;
                        float val = acc[mt][nt][j] + outb[n * 128 + col] +
                                    (float)sP[row * 408 + n * 136 + col];
                        x1r[n][(mt * 2 + nt) * 2 + (j >> 1)][j & 1] = (bf16)val;
                    }
        }
        __syncthreads();   // all sP reads (A-operands) done; P now dead
        // write x1 into sP slots
#pragma unroll
        for (int n = 0; n < 3; ++n)
#pragma unroll
            for (int mt = 0; mt < 2; ++mt)
#pragma unroll
                for (int nt = 0; nt < 2; ++nt)
#pragma unroll
                    for (int j = 0; j < 4; ++j) {
                        int row = mt * 16 + rlo + j, col = wid * 32 + nt * 16 + cl;
                        sP[row * 408 + n * 136 + col] =
                            x1r[n][(mt * 2 + nt) * 2 + (j >> 1)][j & 1];
                    }
        __syncthreads();
#pragma unroll
        for (int it = 0; it < 6; ++it) {
            int p = it * 16 + wid * 4 + (lane >> 4);
            int r = p & 31, nn = p >> 5;
            ln16_bf16(sP + r * 408 + nn * 136, ag_ + nn * 128, ab_ + nn * 128, nullptr, lane & 15);
        }
        __syncthreads();
    }

    // ================= phase 3: FFN -> x2 into sP slots =================
    for (int n = 0; n < 3; ++n) {
        f32x4 fa[2][2];
#pragma unroll
        for (int half = 0; half < 2; ++half) {
            zacc(fa);
            gemm_k128_gw(sP + n * 136, 408, w1 + (long)(n * 256 + half * 128) * 128, 128,
                         lane, wid, fa);
            foreach_acc(fa, lane, wid, [&](int row, int col, float v) {
                float x = v + fb1[n * 256 + half * 128 + col];
                float ge = 0.5f * x * (1.0f + erff(x * 0.70710678118654752f));
                sH[row * 264 + half * 128 + col] = (bf16)ge;
            });
        }
        __syncthreads();   // sH complete
        zacc(fa);
        gemm_k128_gw(sH, 264, w2 + (long)n * 32768, 256, lane, wid, fa);
        gemm_k128_gw(sH + 128, 264, w2 + (long)n * 32768 + 128, 256, lane, wid, fa);
        __syncthreads();   // sH reads done before f32 alias writes
        foreach_acc(fa, lane, wid, [&](int row, int col, float v) {
            sHf[row * 132 + col] = v + fb2[n * 128 + col] + (float)sP[row * 408 + n * 136 + col];
        });
        __syncthreads();
#pragma unroll
        for (int it = 0; it < 2; ++it) {
            int p = it * 16 + wid * 4 + (lane >> 4);
            ln16_f32(sHf + p * 132, fg_ + n * 128, fbb_ + n * 128, lane & 15);
        }
        __syncthreads();
        // f32 -> bf16 into sP slot n (x1 slot n dead)
#pragma unroll
        for (int i = 0; i < 8; ++i) {
            int lin = t + i * 256;           // 0..2047 pairs
            int r = lin >> 6, c2 = (lin & 63) * 2;
            bf16x2 o = {(bf16)sHf[r * 132 + c2], (bf16)sHf[r * 132 + c2 + 1]};
            *(bf16x2*)(sP + r * 408 + n * 136 + c2) = o;
        }
        __syncthreads();
    }

    // ================= phase 4: gates + fused output =================
    float p0[6], p1[6], p2[6];
    const int e = lane * 6;
#pragma unroll
    for (int i = 0; i < 6; ++i) {
        p0[i] = gw[e + i];
        p1[i] = gw[384 + e + i];
        p2[i] = gw[768 + e + i];
    }
    for (int r = wid; r < 32; r += 4) {
        const bf16* xr = sP + r * 408;
        float l0 = 0.f, l1 = 0.f, l2 = 0.f;
#pragma unroll
        for (int i = 0; i < 6; ++i) {
            int f = e + i;
            float x = (float)xr[(f >> 7) * 136 + (f & 127)];
            l0 += x * p0[i]; l1 += x * p1[i]; l2 += x * p2[i];
        }
        l0 = allsum64(l0) + gb[0];
        l1 = allsum64(l1) + gb[1];
        l2 = allsum64(l2) + gb[2];
        float mx = fmaxf(l0, fmaxf(l1, l2));
        float e0 = expf(l0 - mx), e1 = expf(l1 - mx), e2 = expf(l2 - mx);
        float inv = 1.f / (e0 + e1 + e2);
        float g0 = e0 * inv, g1 = e1 * inv, g2 = e2 * inv;
        float o0 = g0 * (float)xr[lane] + g1 * (float)xr[136 + lane] + g2 * (float)xr[272 + lane];
        float o1 = g0 * (float)xr[64 + lane] + g1 * (float)xr[200 + lane] +
                   g2 * (float)xr[336 + lane];
        out[(rowbase + r) * 128 + lane] = o0;
        out[(rowbase + r) * 128 + 64 + lane] = o1;
    }
}

// ---------------------------------------------------------------------------
extern "C" void kernel_launch(void* const* d_in, const int* in_sizes, int n_in,
                              void* d_out, int out_size, void* d_ws, size_t ws_size,
                              hipStream_t stream) {
    const float* xs = (const float*)d_in[0];
    const float* xg = (const float*)d_in[1];
    const float* xf = (const float*)d_in[2];
    const float* w_sp = (const float*)d_in[3];
    const float* w_gf = (const float*)d_in[4];
    const float* proj_b = (const float*)d_in[5];
    const float* proj_g = (const float*)d_in[6];
    const float* proj_bb = (const float*)d_in[7];
    const float* mod_emb = (const float*)d_in[8];
    const float* in_w = (const float*)d_in[9];
    const float* in_b = (const float*)d_in[10];
    const float* out_w = (const float*)d_in[11];
    const float* out_b = (const float*)d_in[12];
    const float* attn_g = (const float*)d_in[13];
    const float* attn_b = (const float*)d_in[14];
    const float* ffn_w1 = (const float*)d_in[15];
    const float* ffn_b1 = (const float*)d_in[16];
    const float* ffn_w2 = (const float*)d_in[17];
    const float* ffn_b2 = (const float*)d_in[18];
    const float* ffn_g = (const float*)d_in[19];
    const float* ffn_bb = (const float*)d_in[20];
    const float* gate_w = (const float*)d_in[21];
    const float* gate_b = (const float*)d_in[22];

    const int B = in_sizes[1] / 128;  // 65536

    bf16* wb = (bf16*)d_ws;
    bf16* wsp = wb;                    // 163840 elems
    bf16* wgf = wb + 163840;           // 32768
    bf16* wqkv = wb + 196608;          // 147456
    bf16* wout = wb + 344064;          // 49152
    bf16* w1 = wb + 393216;            // 98304
    bf16* w2 = wb + 491520;            // 98304

    cvt_all<<<576, 256, 0, stream>>>(w_sp, w_gf, in_w, out_w, ffn_w1, ffn_w2, wb);
    fused_kernel<<<B / 32, 256, 0, stream>>>(
        xs, xg, xf, wsp, wgf, proj_b, proj_g, proj_bb, mod_emb,
        wqkv, wout, in_b, out_b, attn_g, attn_b,
        w1, w2, ffn_b1, ffn_b2, ffn_g, ffn_bb,
        gate_w, gate_b, (float*)d_out);
}